// Round 1
// baseline (485.519 us; speedup 1.0000x reference)
//
#include <hip/hip_runtime.h>

#define NE 50000
#define NR 200
#define EE 800000
#define DD 128
#define HH 8
#define SLOTS 64
#define SLOPE 0.2f

__device__ __forceinline__ float leaky(float x){ return x >= 0.f ? x : SLOPE*x; }

// Butterfly multi-reduce: input part[0..7] split as pa(0..3)/pb(4..7) per lane.
// Lane l (head hh=l&7) returns sum over all 64 lanes of part[hh].
__device__ __forceinline__ float head_reduce(float4 pa, float4 pb, int hh){
  bool b0 = (hh & 1) != 0;
  bool b1 = (hh & 2) != 0;
  bool b2 = (hh & 4) != 0;
  float q0 = (b0 ? pa.y : pa.x) + __shfl_xor(b0 ? pa.x : pa.y, 1, 64);
  float q1 = (b0 ? pa.w : pa.z) + __shfl_xor(b0 ? pa.z : pa.w, 1, 64);
  float q2 = (b0 ? pb.y : pb.x) + __shfl_xor(b0 ? pb.x : pb.y, 1, 64);
  float q3 = (b0 ? pb.w : pb.z) + __shfl_xor(b0 ? pb.z : pb.w, 1, 64);
  float r0 = (b1 ? q1 : q0) + __shfl_xor(b1 ? q0 : q1, 2, 64);
  float r1 = (b1 ? q3 : q2) + __shfl_xor(b1 ? q2 : q3, 2, 64);
  float a  = (b2 ? r1 : r0) + __shfl_xor(b2 ? r0 : r1, 4, 64);
  a += __shfl_xor(a, 8, 64);
  a += __shfl_xor(a, 16, 64);
  a += __shfl_xor(a, 32, 64);
  return a;
}

__global__ void k_zero(int* __restrict__ cnt){
  int i = blockIdx.x*256 + threadIdx.x;
  if (i < NE) cnt[i] = 0;
}

// Scatter edges into per-dst strided slots; cnt[d] becomes the in-degree.
__global__ void k_scatter(const int* __restrict__ edge_index,
                          const int* __restrict__ edge_type,
                          int* __restrict__ cnt, int* __restrict__ slot){
  int e = blockIdx.x*256 + threadIdx.x;
  if (e >= EE) return;
  int s = edge_index[e];        // row 0: src
  int d = edge_index[EE + e];   // row 1: dst
  int t = edge_type[e];
  int pos = atomicAdd(&cnt[d], 1);
  if (pos < SLOTS) slot[d*SLOTS + pos] = s | (t << 16);  // src<2^16, type<2^16
}

// zP3 = z @ P_w[2D:], zWc = z @ Wc_w[D:]
__global__ void k_zsmall(const float* __restrict__ z, const float* __restrict__ P_w,
                         const float* __restrict__ Wc_w,
                         float* __restrict__ zP3, float* __restrict__ zWc){
  int r = blockIdx.x, c = threadIdx.x;
  float a1 = 0.f, a2 = 0.f;
  for (int d = 0; d < DD; d++){
    float zv = z[r*DD + d];
    a1 = fmaf(zv, P_w[(2*DD + d)*DD + c], a1);
    a2 = fmaf(zv, Wc_w[(DD + d)*DD + c], a2);
  }
  zP3[r*DD + c] = a1;
  zWc[r*DD + c] = a2;
}

// hP1 = h@P_w[:D], hP2 = h@P_w[D:2D], hWc = h@Wc_w[:D]
// 64 rows per block; h tile in LDS (padded stride 132 -> conflict-free),
// weights streamed from global (hot in L1/L2, broadcast-read pattern).
__global__ __launch_bounds__(256) void k_hgemm(const float* __restrict__ h,
    const float* __restrict__ P_w, const float* __restrict__ Wc_w,
    float* __restrict__ hP1, float* __restrict__ hP2, float* __restrict__ hWc){
  __shared__ float hs[64][DD + 4];
  int tid = threadIdx.x;
  int row0 = blockIdx.x * 64;
  for (int f = tid; f < 64*DD/4; f += 256){
    int r = f >> 5, c4 = f & 31;
    int gr = row0 + r;
    float4 v = (gr < NE) ? ((const float4*)(h + (size_t)gr*DD))[c4]
                         : make_float4(0.f,0.f,0.f,0.f);
    hs[r][c4*4+0] = v.x; hs[r][c4*4+1] = v.y;
    hs[r][c4*4+2] = v.z; hs[r][c4*4+3] = v.w;
  }
  __syncthreads();
  int r0 = (tid >> 4) * 4, c0 = (tid & 15) * 8;
  #pragma unroll
  for (int mi = 0; mi < 3; mi++){
    const float* W = (mi == 0) ? P_w : (mi == 1) ? (P_w + DD*DD) : Wc_w;
    float*       O = (mi == 0) ? hP1 : (mi == 1) ? hP2 : hWc;
    float acc[4][8];
    #pragma unroll
    for (int i = 0; i < 4; i++)
      #pragma unroll
      for (int j = 0; j < 8; j++) acc[i][j] = 0.f;
    for (int d = 0; d < DD; d++){
      float av[4];
      #pragma unroll
      for (int i = 0; i < 4; i++) av[i] = hs[r0+i][d];
      float4 b0 = *(const float4*)(W + d*DD + c0);
      float4 b1 = *(const float4*)(W + d*DD + c0 + 4);
      float bv[8] = {b0.x,b0.y,b0.z,b0.w,b1.x,b1.y,b1.z,b1.w};
      #pragma unroll
      for (int i = 0; i < 4; i++)
        #pragma unroll
        for (int j = 0; j < 8; j++)
          acc[i][j] = fmaf(av[i], bv[j], acc[i][j]);
    }
    #pragma unroll
    for (int i = 0; i < 4; i++){
      int gr = row0 + r0 + i;
      if (gr < NE){
        *(float4*)(O + (size_t)gr*DD + c0)     = make_float4(acc[i][0],acc[i][1],acc[i][2],acc[i][3]);
        *(float4*)(O + (size_t)gr*DD + c0 + 4) = make_float4(acc[i][4],acc[i][5],acc[i][6],acc[i][7]);
      }
    }
  }
}

// One wave per node: online softmax over incoming edges, fused self-term,
// aggregation, residual, final leaky. Lane l: head hh=l&7, sub=l>>3,
// owns dims d0=hh*16+sub*2, d0+1 (full-row coverage, permuted -> coalesced).
__global__ __launch_bounds__(256) void k_node(
    const float* __restrict__ hP1, const float* __restrict__ hP2,
    const float* __restrict__ hWc, const float* __restrict__ zP3,
    const float* __restrict__ zWc, const float* __restrict__ h,
    const float* __restrict__ y_w, const float* __restrict__ rw_p,
    const int* __restrict__ cnt, const int* __restrict__ slot,
    float* __restrict__ out){
  int lane = threadIdx.x & 63;
  int n = blockIdx.x*4 + (threadIdx.x >> 6);
  if (n >= NE) return;
  int hh  = lane & 7;
  int sub = lane >> 3;
  int di  = hh*8 + sub;          // float2 index within the 128-dim row
  int deg = cnt[n]; if (deg > SLOTS) deg = SLOTS;
  float2 hn = ((const float2*)(h + (size_t)n*DD))[di];
  if (deg == 0){ ((float2*)(out + (size_t)n*DD))[di] = hn; return; }
  float2 p1  = ((const float2*)(hP1 + (size_t)n*DD))[di];
  float2 p2n = ((const float2*)(hP2 + (size_t)n*DD))[di];
  float2 wcn = ((const float2*)(hWc + (size_t)n*DD))[di];
  int d0 = di*2;
  const float4* y4 = (const float4*)(y_w + (size_t)d0*HH);
  float4 A = y4[0], B = y4[1], C = y4[2], Dv = y4[3];  // rows d0 (A,B), d0+1 (C,Dv)
  int my_slot = 0;
  if (lane < deg) my_slot = slot[(size_t)n*SLOTS + lane];
  float m_h = -1e30f, den = 0.f;
  float aggx = 0.f, aggy = 0.f;
  float sP3x = 0.f, sP3y = 0.f, sWcx = 0.f, sWcy = 0.f;
  for (int j = 0; j < deg; j++){
    int v = __shfl(my_slot, j, 64);
    int s = v & 0xFFFF;
    int t = v >> 16;
    float2 a2 = ((const float2*)(hP2 + (size_t)s*DD))[di];
    float2 b2 = ((const float2*)(zP3 + (size_t)t*DD))[di];
    float2 c2 = ((const float2*)(hWc + (size_t)s*DD))[di];
    float2 e2 = ((const float2*)(zWc + (size_t)t*DD))[di];
    sP3x += b2.x; sP3y += b2.y;
    sWcx += e2.x; sWcy += e2.y;
    float l0 = leaky(p1.x + a2.x + b2.x);
    float l1 = leaky(p1.y + a2.y + b2.y);
    float4 pa, pb;
    pa.x = l0*A.x + l1*C.x;  pa.y = l0*A.y + l1*C.y;
    pa.z = l0*A.z + l1*C.z;  pa.w = l0*A.w + l1*C.w;
    pb.x = l0*B.x + l1*Dv.x; pb.y = l0*B.y + l1*Dv.y;
    pb.z = l0*B.z + l1*Dv.z; pb.w = l0*B.w + l1*Dv.w;
    float attn = head_reduce(pa, pb, hh);
    float nm = fmaxf(m_h, attn);
    float sc = __expf(m_h - nm);
    float w  = __expf(attn - nm);
    den = den*sc + w;
    m_h = nm;
    float tx = c2.x + e2.x, ty = c2.y + e2.y;
    aggx = aggx*sc + w*tx;
    aggy = aggy*sc + w*ty;
  }
  // self term
  float invdeg = 1.f/(float)deg;
  float l0 = leaky(p1.x + p2n.x + sP3x*invdeg);
  float l1 = leaky(p1.y + p2n.y + sP3y*invdeg);
  float4 pa, pb;
  pa.x = l0*A.x + l1*C.x;  pa.y = l0*A.y + l1*C.y;
  pa.z = l0*A.z + l1*C.z;  pa.w = l0*A.w + l1*C.w;
  pb.x = l0*B.x + l1*Dv.x; pb.y = l0*B.y + l1*Dv.y;
  pb.z = l0*B.z + l1*Dv.z; pb.w = l0*B.w + l1*Dv.w;
  float attnS = head_reduce(pa, pb, hh);
  float nm = fmaxf(m_h, attnS);
  float sc = __expf(m_h - nm);
  float w  = __expf(attnS - nm);
  den = den*sc + w;
  float tx = wcn.x + sWcx*invdeg, ty = wcn.y + sWcy*invdeg;
  aggx = aggx*sc + w*tx;
  aggy = aggy*sc + w*ty;
  float rw = rw_p[0];
  float inv_den = 1.f/den;
  float o0 = leaky(aggx*inv_den + rw*hn.x);
  float o1 = leaky(aggy*inv_den + rw*hn.y);
  ((float2*)(out + (size_t)n*DD))[di] = make_float2(o0, o1);
}

extern "C" void kernel_launch(void* const* d_in, const int* in_sizes, int n_in,
                              void* d_out, int out_size, void* d_ws, size_t ws_size,
                              hipStream_t stream){
  const float* h    = (const float*)d_in[0];
  const float* z    = (const float*)d_in[1];
  const float* Wc_w = (const float*)d_in[2];
  const float* P_w  = (const float*)d_in[3];
  const float* y_w  = (const float*)d_in[4];
  const float* rw   = (const float*)d_in[5];
  const int* edge_index = (const int*)d_in[6];
  const int* edge_type  = (const int*)d_in[7];
  float* out = (float*)d_out;

  char* ws = (char*)d_ws;
  float* hP1 = (float*)ws;  ws += (size_t)NE*DD*4;
  float* hP2 = (float*)ws;  ws += (size_t)NE*DD*4;
  float* hWc = (float*)ws;  ws += (size_t)NE*DD*4;
  float* zP3 = (float*)ws;  ws += (size_t)NR*DD*4;
  float* zWc = (float*)ws;  ws += (size_t)NR*DD*4;
  int*   cnt = (int*)ws;    ws += (size_t)NE*4;
  int*   slot= (int*)ws;    ws += (size_t)NE*SLOTS*4;

  hipLaunchKernelGGL(k_zero,    dim3((NE+255)/256), dim3(256), 0, stream, cnt);
  hipLaunchKernelGGL(k_scatter, dim3((EE+255)/256), dim3(256), 0, stream,
                     edge_index, edge_type, cnt, slot);
  hipLaunchKernelGGL(k_zsmall,  dim3(NR), dim3(DD), 0, stream, z, P_w, Wc_w, zP3, zWc);
  hipLaunchKernelGGL(k_hgemm,   dim3((NE+63)/64), dim3(256), 0, stream,
                     h, P_w, Wc_w, hP1, hP2, hWc);
  hipLaunchKernelGGL(k_node,    dim3((NE+3)/4), dim3(256), 0, stream,
                     hP1, hP2, hWc, zP3, zWc, h, y_w, rw, cnt, slot, out);
}

// Round 2
// 452.904 us; speedup vs baseline: 1.0720x; 1.0720x over previous
//
#include <hip/hip_runtime.h>

#define NE 50000
#define NR 200
#define EE 800000
#define DD 128
#define HH 8
#define SLOTS 64
#define SLOPE 0.2f

__device__ __forceinline__ float leaky(float x){ return x >= 0.f ? x : SLOPE*x; }

// Butterfly multi-reduce: input part[0..7] split as pa(0..3)/pb(4..7) per lane.
// Lane l (head hh=l&7) returns sum over all 64 lanes of part[hh].
__device__ __forceinline__ float head_reduce(float4 pa, float4 pb, int hh){
  bool b0 = (hh & 1) != 0;
  bool b1 = (hh & 2) != 0;
  bool b2 = (hh & 4) != 0;
  float q0 = (b0 ? pa.y : pa.x) + __shfl_xor(b0 ? pa.x : pa.y, 1, 64);
  float q1 = (b0 ? pa.w : pa.z) + __shfl_xor(b0 ? pa.z : pa.w, 1, 64);
  float q2 = (b0 ? pb.y : pb.x) + __shfl_xor(b0 ? pb.x : pb.y, 1, 64);
  float q3 = (b0 ? pb.w : pb.z) + __shfl_xor(b0 ? pb.z : pb.w, 1, 64);
  float r0 = (b1 ? q1 : q0) + __shfl_xor(b1 ? q0 : q1, 2, 64);
  float r1 = (b1 ? q3 : q2) + __shfl_xor(b1 ? q2 : q3, 2, 64);
  float a  = (b2 ? r1 : r0) + __shfl_xor(b2 ? r0 : r1, 4, 64);
  a += __shfl_xor(a, 8, 64);
  a += __shfl_xor(a, 16, 64);
  a += __shfl_xor(a, 32, 64);
  return a;
}

__device__ __forceinline__ float edge_attn(float2 p1, float2 a, float2 b,
    float4 A, float4 B, float4 C, float4 Dv, int hh){
  float l0 = leaky(p1.x + a.x + b.x);
  float l1 = leaky(p1.y + a.y + b.y);
  float4 pa, pb;
  pa.x = l0*A.x + l1*C.x;  pa.y = l0*A.y + l1*C.y;
  pa.z = l0*A.z + l1*C.z;  pa.w = l0*A.w + l1*C.w;
  pb.x = l0*B.x + l1*Dv.x; pb.y = l0*B.y + l1*Dv.y;
  pb.z = l0*B.z + l1*Dv.z; pb.w = l0*B.w + l1*Dv.w;
  return head_reduce(pa, pb, hh);
}

__device__ __forceinline__ void sm_update(float attn, float tx, float ty,
    float& m_h, float& den, float& aggx, float& aggy){
  float nm = fmaxf(m_h, attn);
  float sc = __expf(m_h - nm);
  float w  = __expf(attn - nm);
  den = den*sc + w;
  m_h = nm;
  aggx = aggx*sc + w*tx;
  aggy = aggy*sc + w*ty;
}

__global__ void k_zero(int* __restrict__ cnt){
  int i = blockIdx.x*256 + threadIdx.x;
  if (i < NE) cnt[i] = 0;
}

// Scatter edges into per-dst strided slots; cnt[d] becomes the in-degree.
__global__ void k_scatter(const int* __restrict__ edge_index,
                          const int* __restrict__ edge_type,
                          int* __restrict__ cnt, int* __restrict__ slot){
  int e = blockIdx.x*256 + threadIdx.x;
  if (e >= EE) return;
  int s = edge_index[e];        // row 0: src
  int d = edge_index[EE + e];   // row 1: dst
  int t = edge_type[e];
  int pos = atomicAdd(&cnt[d], 1);
  if (pos < SLOTS) slot[d*SLOTS + pos] = s | (t << 16);  // src<2^16, type<2^16
}

// zPW row r (256 floats): [ z@P3 | z@Wc_z ]
__global__ void k_zsmall(const float* __restrict__ z, const float* __restrict__ P_w,
                         const float* __restrict__ Wc_w, float* __restrict__ zPW){
  int r = blockIdx.x, c = threadIdx.x;
  float a1 = 0.f, a2 = 0.f;
  for (int d = 0; d < DD; d++){
    float zv = z[r*DD + d];
    a1 = fmaf(zv, P_w[(2*DD + d)*DD + c], a1);
    a2 = fmaf(zv, Wc_w[(DD + d)*DD + c], a2);
  }
  zPW[(size_t)r*(2*DD) + c]      = a1;
  zPW[(size_t)r*(2*DD) + DD + c] = a2;
}

// hP1 = h@P_w[:D] (own table); hPW row n (256 floats): [ h@P2 | h@Wc_h ]
__global__ __launch_bounds__(256) void k_hgemm(const float* __restrict__ h,
    const float* __restrict__ P_w, const float* __restrict__ Wc_w,
    float* __restrict__ hP1, float* __restrict__ hPW){
  __shared__ float hs[64][DD + 4];
  int tid = threadIdx.x;
  int row0 = blockIdx.x * 64;
  for (int f = tid; f < 64*DD/4; f += 256){
    int r = f >> 5, c4 = f & 31;
    int gr = row0 + r;
    float4 v = (gr < NE) ? ((const float4*)(h + (size_t)gr*DD))[c4]
                         : make_float4(0.f,0.f,0.f,0.f);
    hs[r][c4*4+0] = v.x; hs[r][c4*4+1] = v.y;
    hs[r][c4*4+2] = v.z; hs[r][c4*4+3] = v.w;
  }
  __syncthreads();
  int r0 = (tid >> 4) * 4, c0 = (tid & 15) * 8;
  #pragma unroll
  for (int mi = 0; mi < 3; mi++){
    const float* W = (mi == 0) ? P_w : (mi == 1) ? (P_w + DD*DD) : Wc_w;
    float acc[4][8];
    #pragma unroll
    for (int i = 0; i < 4; i++)
      #pragma unroll
      for (int j = 0; j < 8; j++) acc[i][j] = 0.f;
    for (int d4 = 0; d4 < DD/4; d4++){
      float avs[4][4];
      #pragma unroll
      for (int i = 0; i < 4; i++)
        *(float4*)&avs[i][0] = *(const float4*)&hs[r0+i][d4*4];
      #pragma unroll
      for (int dd = 0; dd < 4; dd++){
        int d = d4*4 + dd;
        float4 b0 = *(const float4*)(W + d*DD + c0);
        float4 b1 = *(const float4*)(W + d*DD + c0 + 4);
        float bv[8] = {b0.x,b0.y,b0.z,b0.w,b1.x,b1.y,b1.z,b1.w};
        #pragma unroll
        for (int i = 0; i < 4; i++)
          #pragma unroll
          for (int j = 0; j < 8; j++)
            acc[i][j] = fmaf(avs[i][dd], bv[j], acc[i][j]);
      }
    }
    #pragma unroll
    for (int i = 0; i < 4; i++){
      int gr = row0 + r0 + i;
      if (gr < NE){
        float* O = (mi == 0) ? (hP1 + (size_t)gr*DD + c0)
                 : (mi == 1) ? (hPW + (size_t)gr*(2*DD) + c0)
                             : (hPW + (size_t)gr*(2*DD) + DD + c0);
        *(float4*)(O)     = make_float4(acc[i][0],acc[i][1],acc[i][2],acc[i][3]);
        *(float4*)(O + 4) = make_float4(acc[i][4],acc[i][5],acc[i][6],acc[i][7]);
      }
    }
  }
}

// One wave per node: online softmax over incoming edges, fused self-term,
// aggregation, residual, final leaky. Lane l: head hh=l&7, sub=l>>3,
// owns float2 di=hh*8+sub (dims 2*di, 2*di+1). Edge loop unrolled x4 with
// readlane -> scalar gather bases (SGPR addressing, 16 loads in flight).
__global__ __launch_bounds__(256) void k_node(
    const float* __restrict__ hP1, const float* __restrict__ hPW,
    const float* __restrict__ zPW, const float* __restrict__ h,
    const float* __restrict__ y_w, const float* __restrict__ rw_p,
    const int* __restrict__ cnt, const int* __restrict__ slot,
    float* __restrict__ out){
  int lane = threadIdx.x & 63;
  int n = blockIdx.x*4 + (threadIdx.x >> 6);
  if (n >= NE) return;
  int hh  = lane & 7;
  int sub = lane >> 3;
  int di  = hh*8 + sub;          // float2 index within the 128-dim row
  int d0  = di*2;
  int deg = cnt[n]; if (deg > SLOTS) deg = SLOTS;
  float2 hn = ((const float2*)(h + (size_t)n*DD))[di];
  if (deg == 0){ ((float2*)(out + (size_t)n*DD))[di] = hn; return; }
  float2 p1  = ((const float2*)(hP1 + (size_t)n*DD))[di];
  const float* rowN = hPW + (size_t)n*(2*DD);
  float2 p2n = *(const float2*)(rowN + d0);
  float2 wcn = *(const float2*)(rowN + DD + d0);
  const float4* y4 = (const float4*)(y_w + (size_t)d0*HH);
  float4 A = y4[0], B = y4[1], C = y4[2], Dv = y4[3];  // y rows d0 (A,B), d0+1 (C,Dv)
  int my_slot = 0;
  if (lane < deg) my_slot = slot[(size_t)n*SLOTS + lane];
  float m_h = -1e30f, den = 0.f;
  float aggx = 0.f, aggy = 0.f;
  float sP3x = 0.f, sP3y = 0.f, sWcx = 0.f, sWcy = 0.f;
  int j = 0;
  for (; j + 4 <= deg; j += 4){
    float2 av[4], bv[4], cv[4], ev[4];
    #pragma unroll
    for (int k = 0; k < 4; k++){
      int v = __builtin_amdgcn_readlane(my_slot, j + k);   // SGPR
      const float* rp = hPW + (size_t)(v & 0xFFFF)*(2*DD);
      const float* zp = zPW + (size_t)((unsigned)v >> 16)*(2*DD);
      av[k] = *(const float2*)(rp + d0);
      cv[k] = *(const float2*)(rp + DD + d0);
      bv[k] = *(const float2*)(zp + d0);
      ev[k] = *(const float2*)(zp + DD + d0);
    }
    float at[4];
    #pragma unroll
    for (int k = 0; k < 4; k++){
      sP3x += bv[k].x; sP3y += bv[k].y;
      sWcx += ev[k].x; sWcy += ev[k].y;
      at[k] = edge_attn(p1, av[k], bv[k], A, B, C, Dv, hh);
    }
    #pragma unroll
    for (int k = 0; k < 4; k++)
      sm_update(at[k], cv[k].x + ev[k].x, cv[k].y + ev[k].y, m_h, den, aggx, aggy);
  }
  for (; j < deg; j++){
    int v = __builtin_amdgcn_readlane(my_slot, j);
    const float* rp = hPW + (size_t)(v & 0xFFFF)*(2*DD);
    const float* zp = zPW + (size_t)((unsigned)v >> 16)*(2*DD);
    float2 a2 = *(const float2*)(rp + d0);
    float2 c2 = *(const float2*)(rp + DD + d0);
    float2 b2 = *(const float2*)(zp + d0);
    float2 e2 = *(const float2*)(zp + DD + d0);
    sP3x += b2.x; sP3y += b2.y;
    sWcx += e2.x; sWcy += e2.y;
    float at = edge_attn(p1, a2, b2, A, B, C, Dv, hh);
    sm_update(at, c2.x + e2.x, c2.y + e2.y, m_h, den, aggx, aggy);
  }
  // self term
  float invdeg = 1.f/(float)deg;
  float2 zb1 = make_float2(sP3x*invdeg, sP3y*invdeg);
  float attnS = edge_attn(p1, p2n, zb1, A, B, C, Dv, hh);
  float nm = fmaxf(m_h, attnS);
  float sc = __expf(m_h - nm);
  float w  = __expf(attnS - nm);
  den = den*sc + w;
  float tx = wcn.x + sWcx*invdeg, ty = wcn.y + sWcy*invdeg;
  aggx = aggx*sc + w*tx;
  aggy = aggy*sc + w*ty;
  float rw = rw_p[0];
  float inv_den = 1.f/den;
  float o0 = leaky(aggx*inv_den + rw*hn.x);
  float o1 = leaky(aggy*inv_den + rw*hn.y);
  ((float2*)(out + (size_t)n*DD))[di] = make_float2(o0, o1);
}

extern "C" void kernel_launch(void* const* d_in, const int* in_sizes, int n_in,
                              void* d_out, int out_size, void* d_ws, size_t ws_size,
                              hipStream_t stream){
  const float* h    = (const float*)d_in[0];
  const float* z    = (const float*)d_in[1];
  const float* Wc_w = (const float*)d_in[2];
  const float* P_w  = (const float*)d_in[3];
  const float* y_w  = (const float*)d_in[4];
  const float* rw   = (const float*)d_in[5];
  const int* edge_index = (const int*)d_in[6];
  const int* edge_type  = (const int*)d_in[7];
  float* out = (float*)d_out;

  char* ws = (char*)d_ws;
  float* hP1 = (float*)ws;  ws += (size_t)NE*DD*4;
  float* hPW = (float*)ws;  ws += (size_t)NE*2*DD*4;
  float* zPW = (float*)ws;  ws += (size_t)NR*2*DD*4;
  int*   cnt = (int*)ws;    ws += (size_t)NE*4;
  int*   slot= (int*)ws;    ws += (size_t)NE*SLOTS*4;

  hipLaunchKernelGGL(k_zero,    dim3((NE+255)/256), dim3(256), 0, stream, cnt);
  hipLaunchKernelGGL(k_scatter, dim3((EE+255)/256), dim3(256), 0, stream,
                     edge_index, edge_type, cnt, slot);
  hipLaunchKernelGGL(k_zsmall,  dim3(NR), dim3(DD), 0, stream, z, P_w, Wc_w, zPW);
  hipLaunchKernelGGL(k_hgemm,   dim3((NE+63)/64), dim3(256), 0, stream,
                     h, P_w, Wc_w, hP1, hPW);
  hipLaunchKernelGGL(k_node,    dim3((NE+3)/4), dim3(256), 0, stream,
                     hP1, hPW, zPW, h, y_w, rw, cnt, slot, out);
}